// Round 1
// baseline (214.359 us; speedup 1.0000x reference)
//
#include <hip/hip_runtime.h>

#define B_ 8
#define N_ 4096
#define C_ 512

typedef _Float16 f16;
typedef __attribute__((ext_vector_type(8))) _Float16 f16x8;
typedef __attribute__((ext_vector_type(4))) _Float16 f16x4;
typedef __attribute__((ext_vector_type(4))) float f32x4;

#define TILE_E (128 * 32)

// global -> LDS async copy, 16B per lane. LDS dest must be wave-uniform base;
// lane adds l*16 in hardware. Global src is per-lane.
#define GLL16(gsrc, ldst)                                                      \
  __builtin_amdgcn_global_load_lds(                                            \
      (const __attribute__((address_space(1))) void*)(gsrc),                   \
      (__attribute__((address_space(3))) void*)(ldst), 16, 0, 0)

// ---------------------------------------------------------------------------
// Shared GEMM mainloop: C[128x128] += A[128xK] * B^T[128xK]
// A stored [M][lda] row-major (K contiguous), B stored [N][ldb] row-major
// (K contiguous).  BK=32, fp16, mfma_f32_16x16x32_f16, fp32 accum.
// Block = 256 threads = 4 waves in 2x2; each wave owns a 64x64 quadrant as
// 4x4 fragments of 16x16.
// ---------------------------------------------------------------------------
__device__ __forceinline__ void run_mainloop(const f16* __restrict__ Atile,
                                             const f16* __restrict__ Btile,
                                             int lda, int ldb, int nk,
                                             f16* As, f16* Bs,
                                             f32x4 (&acc)[4][4]) {
  const int tid = threadIdx.x;
  const int lane = tid & 63;
  const int wave = tid >> 6;
  const int wr = wave >> 1, wc = wave & 1;

  // stage one 128x32 fp16 tile (8KB) for A and B into LDS buffer `buf`.
  // 512 chunks of 16B; each thread does 2 chunks per matrix.
  auto stage = [&](int buf, int kt) {
#pragma unroll
    for (int j = 0; j < 2; ++j) {
      const int idx = j * 256 + wave * 64 + lane;  // chunk id in [0,512)
      const int row = idx >> 2;                    // tile row
      const int kc = idx & 3;                      // 8-elem chunk within row
      GLL16(Atile + (size_t)row * lda + kt * 32 + kc * 8,
            As + buf * TILE_E + (j * 256 + wave * 64) * 8);
      GLL16(Btile + (size_t)row * ldb + kt * 32 + kc * 8,
            Bs + buf * TILE_E + (j * 256 + wave * 64) * 8);
    }
  };

  stage(0, 0);
  __syncthreads();
  for (int kt = 0; kt < nk; ++kt) {
    const int buf = kt & 1;
    if (kt + 1 < nk) stage(buf ^ 1, kt + 1);
    const f16* aB = As + buf * TILE_E;
    const f16* bB = Bs + buf * TILE_E;
    f16x8 af[4], bf[4];
#pragma unroll
    for (int i = 0; i < 4; ++i)
      af[i] = *(const f16x8*)(aB + (wr * 64 + i * 16 + (lane & 15)) * 32 +
                              ((lane >> 4) * 8));
#pragma unroll
    for (int j = 0; j < 4; ++j)
      bf[j] = *(const f16x8*)(bB + (wc * 64 + j * 16 + (lane & 15)) * 32 +
                              ((lane >> 4) * 8));
#pragma unroll
    for (int i = 0; i < 4; ++i)
#pragma unroll
      for (int j = 0; j < 4; ++j)
        acc[i][j] =
            __builtin_amdgcn_mfma_f32_16x16x32_f16(af[i], bf[j], acc[i][j],
                                                   0, 0, 0);
    __syncthreads();
  }
}

#define ZERO_ACC(acc)                                                          \
  f32x4 acc[4][4];                                                             \
  _Pragma("unroll") for (int zi = 0; zi < 4; ++zi)                             \
      _Pragma("unroll") for (int zj = 0; zj < 4; ++zj) {                       \
    f32x4 z = {0.f, 0.f, 0.f, 0.f};                                            \
    acc[zi][zj] = z;                                                           \
  }

// --------------------------- prep kernels ----------------------------------
__global__ void __launch_bounds__(256) k_cvt_x(const float* __restrict__ in,
                                               f16* __restrict__ out) {
  const int i = blockIdx.x * 256 + threadIdx.x;  // over n/4
  float4 v = ((const float4*)in)[i];
  f16x4 h = {(f16)v.x, (f16)v.y, (f16)v.z, (f16)v.w};
  ((f16x4*)out)[i] = h;
}

// w [512][cols] fp32 -> wt [cols][512] fp16 (transpose + convert)
__global__ void __launch_bounds__(256) k_transpose_w(const float* __restrict__ w,
                                                     f16* __restrict__ wt,
                                                     int cols) {
  const int idx = blockIdx.x * 256 + threadIdx.x;  // over cols*512
  const int n = idx >> 9;
  const int c = idx & 511;
  wt[idx] = (f16)w[(size_t)c * cols + n];
}

// --------------------------- GEMM kernels ----------------------------------
// qkv = relu(x @ Wqkv + b); writes q^T,k^T [C][N] fp16, v [N][C] fp16
__global__ void __launch_bounds__(256)
    k_gemm_qkv(const f16* __restrict__ x16, const f16* __restrict__ wqkvt,
               const float* __restrict__ bqkv, f16* __restrict__ q_t,
               f16* __restrict__ k_t, f16* __restrict__ v16) {
  __shared__ alignas(16) f16 As[2 * TILE_E];
  __shared__ alignas(16) f16 Bs[2 * TILE_E];
  const int b = blockIdx.z;
  const f16* Atile = x16 + ((size_t)b * N_ + blockIdx.y * 128) * C_;
  const f16* Btile = wqkvt + (size_t)blockIdx.x * 128 * C_;
  ZERO_ACC(acc);
  run_mainloop(Atile, Btile, C_, C_, C_ / 32, As, Bs, acc);

  const int tid = threadIdx.x, lane = tid & 63, wave = tid >> 6;
  const int wr = wave >> 1, wc = wave & 1;
  const int colbase = blockIdx.x * 128 + wc * 64;
  const int rowbase = blockIdx.y * 128 + wr * 64;
#pragma unroll
  for (int j = 0; j < 4; ++j) {
    const int col = colbase + j * 16 + (lane & 15);  // in [0,1536)
    const float bias = bqkv[col];
    const int sec = col >> 9;      // 0=q 1=k 2=v (uniform per fragment)
    const int cch = col & 511;
#pragma unroll
    for (int i = 0; i < 4; ++i) {
      const int n0 = rowbase + i * 16 + ((lane >> 4) << 2);
      f32x4 a = acc[i][j];
      f16x4 h = {(f16)fmaxf(a[0] + bias, 0.f), (f16)fmaxf(a[1] + bias, 0.f),
                 (f16)fmaxf(a[2] + bias, 0.f), (f16)fmaxf(a[3] + bias, 0.f)};
      if (sec == 0) {
        *(f16x4*)(q_t + ((size_t)b * C_ + cch) * N_ + n0) = h;
      } else if (sec == 1) {
        *(f16x4*)(k_t + ((size_t)b * C_ + cch) * N_ + n0) = h;
      } else {
        f16* dst = v16 + ((size_t)b * N_ + n0) * C_ + cch;
        dst[0] = h[0];
        dst[C_] = h[1];
        dst[2 * C_] = h[2];
        dst[3 * C_] = h[3];
      }
    }
  }
}

// scores partial: spart[sp][b][c][d] = sum_{n in split} q[n,c]k[n,d]  (raw)
__global__ void __launch_bounds__(256)
    k_gemm_scores(const f16* __restrict__ q_t, const f16* __restrict__ k_t,
                  float* __restrict__ spart) {
  __shared__ alignas(16) f16 As[2 * TILE_E];
  __shared__ alignas(16) f16 Bs[2 * TILE_E];
  const int z = blockIdx.z, b = z >> 2, sp = z & 3;
  const f16* Atile =
      q_t + (size_t)b * C_ * N_ + (size_t)blockIdx.y * 128 * N_ + sp * 1024;
  const f16* Btile =
      k_t + (size_t)b * C_ * N_ + (size_t)blockIdx.x * 128 * N_ + sp * 1024;
  ZERO_ACC(acc);
  run_mainloop(Atile, Btile, N_, N_, 1024 / 32, As, Bs, acc);

  const int tid = threadIdx.x, lane = tid & 63, wave = tid >> 6;
  const int wr = wave >> 1, wc = wave & 1;
  float* base = spart + (size_t)(sp * B_ + b) * C_ * C_;
  const int colbase = blockIdx.x * 128 + wc * 64;
  const int rowbase = blockIdx.y * 128 + wr * 64;
#pragma unroll
  for (int j = 0; j < 4; ++j) {
    const int d = colbase + j * 16 + (lane & 15);
#pragma unroll
    for (int i = 0; i < 4; ++i) {
      const int c0 = rowbase + i * 16 + ((lane >> 4) << 2);
#pragma unroll
      for (int r = 0; r < 4; ++r)
        base[(size_t)(c0 + r) * C_ + d] = acc[i][j][r];
    }
  }
}

// attn = softmax(sum(spart)*scale, axis=-1) * adj  -> fp16
__global__ void __launch_bounds__(256)
    k_softmax_gate(const float* __restrict__ spart,
                   const float* __restrict__ adj, f16* __restrict__ attn) {
  const int b = blockIdx.x >> 9, c = blockIdx.x & 511;
  const int tid = threadIdx.x;
  const size_t ro = ((size_t)b * C_ + c) * C_;
  float s0 = 0.f, s1 = 0.f;
#pragma unroll
  for (int sp = 0; sp < 4; ++sp) {
    const float* p = spart + (size_t)sp * B_ * C_ * C_ + ro;
    s0 += p[tid];
    s1 += p[tid + 256];
  }
  const float scale = 0.044194173824159216f;  // 1/sqrt(512)
  const float v0 = s0 * scale, v1 = s1 * scale;

  __shared__ float red[256];
  red[tid] = fmaxf(v0, v1);
  __syncthreads();
  for (int s = 128; s > 0; s >>= 1) {
    if (tid < s) red[tid] = fmaxf(red[tid], red[tid + s]);
    __syncthreads();
  }
  const float mx = red[0];
  __syncthreads();
  const float e0 = __expf(v0 - mx), e1 = __expf(v1 - mx);
  red[tid] = e0 + e1;
  __syncthreads();
  for (int s = 128; s > 0; s >>= 1) {
    if (tid < s) red[tid] += red[tid + s];
    __syncthreads();
  }
  const float inv = 1.0f / red[0];
  attn[ro + tid] = (f16)(e0 * inv * adj[ro + tid]);
  attn[ro + tid + 256] = (f16)(e1 * inv * adj[ro + tid + 256]);
}

// M^T[e][c] = sum_d attn[c][d] * Wo[d][e]
__global__ void __launch_bounds__(256)
    k_gemm_m(const f16* __restrict__ attn, const f16* __restrict__ wot,
             f16* __restrict__ mt) {
  __shared__ alignas(16) f16 As[2 * TILE_E];
  __shared__ alignas(16) f16 Bs[2 * TILE_E];
  const int b = blockIdx.z;
  const f16* Atile = attn + (size_t)b * C_ * C_ + (size_t)blockIdx.y * 128 * C_;
  const f16* Btile = wot + (size_t)blockIdx.x * 128 * C_;
  ZERO_ACC(acc);
  run_mainloop(Atile, Btile, C_, C_, C_ / 32, As, Bs, acc);

  const int tid = threadIdx.x, lane = tid & 63, wave = tid >> 6;
  const int wr = wave >> 1, wc = wave & 1;
  f16* base = mt + (size_t)b * C_ * C_;
  const int colbase = blockIdx.x * 128 + wc * 64;
  const int rowbase = blockIdx.y * 128 + wr * 64;
#pragma unroll
  for (int j = 0; j < 4; ++j) {
    const int e = colbase + j * 16 + (lane & 15);
#pragma unroll
    for (int i = 0; i < 4; ++i) {
      const int c0 = rowbase + i * 16 + ((lane >> 4) << 2);
      f32x4 a = acc[i][j];
      f16x4 h = {(f16)a[0], (f16)a[1], (f16)a[2], (f16)a[3]};
      *(f16x4*)(base + (size_t)e * C_ + c0) = h;  // transposed store
    }
  }
}

// out[n][e] = sum_c v[n][c] * M[c][e] + bo[e]   (fp32 out)
__global__ void __launch_bounds__(256)
    k_gemm_out(const f16* __restrict__ v16, const f16* __restrict__ mt,
               const float* __restrict__ bo, float* __restrict__ out) {
  __shared__ alignas(16) f16 As[2 * TILE_E];
  __shared__ alignas(16) f16 Bs[2 * TILE_E];
  const int b = blockIdx.z;
  const f16* Atile = v16 + ((size_t)b * N_ + blockIdx.y * 128) * C_;
  const f16* Btile = mt + (size_t)b * C_ * C_ + (size_t)blockIdx.x * 128 * C_;
  ZERO_ACC(acc);
  run_mainloop(Atile, Btile, C_, C_, C_ / 32, As, Bs, acc);

  const int tid = threadIdx.x, lane = tid & 63, wave = tid >> 6;
  const int wr = wave >> 1, wc = wave & 1;
  float* base = out + (size_t)b * N_ * C_;
  const int colbase = blockIdx.x * 128 + wc * 64;
  const int rowbase = blockIdx.y * 128 + wr * 64;
#pragma unroll
  for (int j = 0; j < 4; ++j) {
    const int e = colbase + j * 16 + (lane & 15);
    const float bias = bo[e];
#pragma unroll
    for (int i = 0; i < 4; ++i) {
      const int n0 = rowbase + i * 16 + ((lane >> 4) << 2);
#pragma unroll
      for (int r = 0; r < 4; ++r)
        base[(size_t)(n0 + r) * C_ + e] = acc[i][j][r] + bias;
    }
  }
}

// ---------------------------------------------------------------------------
extern "C" void kernel_launch(void* const* d_in, const int* in_sizes, int n_in,
                              void* d_out, int out_size, void* d_ws,
                              size_t ws_size, hipStream_t stream) {
  const float* x = (const float*)d_in[0];
  const float* adj = (const float*)d_in[1];
  const float* Wqkv = (const float*)d_in[2];
  const float* bqkv = (const float*)d_in[3];
  const float* Wo = (const float*)d_in[4];
  const float* bo = (const float*)d_in[5];
  float* out = (float*)d_out;

  char* ws = (char*)d_ws;
  size_t off = 0;
  auto carve = [&](size_t bytes) -> char* {
    char* p = ws + off;
    off += (bytes + 255) & ~(size_t)255;
    return p;
  };
  f16* x16 = (f16*)carve((size_t)B_ * N_ * C_ * 2);       // 33.6 MB
  f16* wqkvt = (f16*)carve((size_t)3 * C_ * C_ * 2);      // 1.6 MB
  f16* wot = (f16*)carve((size_t)C_ * C_ * 2);            // 0.5 MB
  f16* q_t = (f16*)carve((size_t)B_ * C_ * N_ * 2);       // 33.6 MB
  f16* k_t = (f16*)carve((size_t)B_ * C_ * N_ * 2);       // 33.6 MB
  f16* v16 = (f16*)carve((size_t)B_ * N_ * C_ * 2);       // 33.6 MB
  // aliases over dead buffers (launch order guarantees no overlap in liveness)
  float* spart = (float*)x16;   // 4*8*512*512*4 = 33.6 MB, x16 dead after qkv
  f16* attn16 = k_t;            // 4.2 MB, k_t dead after scores
  f16* mt16 = q_t;              // 4.2 MB, q_t dead after scores

  k_cvt_x<<<(B_ * N_ * C_ / 4) / 256, 256, 0, stream>>>(x, x16);
  k_transpose_w<<<(C_ * 3 * C_) / 256, 256, 0, stream>>>(Wqkv, wqkvt, 3 * C_);
  k_transpose_w<<<(C_ * C_) / 256, 256, 0, stream>>>(Wo, wot, C_);
  k_gemm_qkv<<<dim3(12, 32, B_), 256, 0, stream>>>(x16, wqkvt, bqkv, q_t, k_t,
                                                   v16);
  k_gemm_scores<<<dim3(4, 4, B_ * 4), 256, 0, stream>>>(q_t, k_t, spart);
  k_softmax_gate<<<B_ * C_, 256, 0, stream>>>(spart, adj, attn16);
  k_gemm_m<<<dim3(4, 4, B_), 256, 0, stream>>>(attn16, wot, mt16);
  k_gemm_out<<<dim3(4, 32, B_), 256, 0, stream>>>(v16, mt16, bo, out);
}

// Round 2
// 198.613 us; speedup vs baseline: 1.0793x; 1.0793x over previous
//
#include <hip/hip_runtime.h>

#define B_ 8
#define N_ 4096
#define C_ 512

typedef _Float16 f16;
typedef __attribute__((ext_vector_type(8))) _Float16 f16x8;
typedef __attribute__((ext_vector_type(4))) _Float16 f16x4;
typedef __attribute__((ext_vector_type(4))) float f32x4;

#define TILE_E (128 * 32)

// global -> LDS async copy, 16B per lane. LDS dest must be wave-uniform base;
// lane adds l*16 in hardware. Global src is per-lane.
#define GLL16(gsrc, ldst)                                                      \
  __builtin_amdgcn_global_load_lds(                                            \
      (const __attribute__((address_space(1))) void*)(gsrc),                   \
      (__attribute__((address_space(3))) void*)(ldst), 16, 0, 0)

__device__ __forceinline__ int xcd_remap(int bid, int nwg) {
  // nwg % 8 == 0 for all our grids -> bijective chunked remap (T1)
  return (bid & 7) * (nwg >> 3) + (bid >> 3);
}

// ---------------------------------------------------------------------------
// 8-phase 256x256 mainloop (BK=64, 8 waves as 2Mx4N, per-wave 128x64 output).
// A stored [M][LDA], B stored [N][LDB], both K-contiguous f16.
// LDS: 4 half-slots per matrix of [128][64] f16 (16KB each) = 128KB total,
// st_16x32 XOR-swizzled (byte ^= ((byte>>9)&1)<<5).
// Schedule per tile T (4 phases):
//   ph1: stage(T+1,B1); read ALL 24 frags; bar; lgkmcnt(0); 16 MFMA(k0,M0-3); bar
//   ph2: stage(T+2,A0); bar; 16 MFMA(k0,M4-7); bar
//   ph3: stage(T+2,A1); bar; 16 MFMA(k1,M0-3); bar
//   ph4: stage(T+2,B0); vmcnt(6|0); bar; 16 MFMA(k1,M4-7); bar
// Slot-reuse safety: all LDS reads of tile T drain (lgkmcnt0) before ph1's end
// barrier, so stages at ph2..4 (targeting tile T's slots for T+2) are ordered
// after every wave's reads. vmcnt(6) leaves exactly the 3 newest half-tiles
// (T+2's A0,A1,B0) in flight -> tile T+1 proven resident at ph4.
// ---------------------------------------------------------------------------
#define SBAR() asm volatile("s_barrier" ::: "memory")
#define SFENCE() __builtin_amdgcn_sched_barrier(0)

template <int LDA, int LDB, int NT>
__device__ __forceinline__ void mainloop8(const f16* __restrict__ Ag,
                                          const f16* __restrict__ Bg,
                                          f16* Als, f16* Bls,
                                          f32x4 (&acc)[8][4]) {
  const int tid = threadIdx.x;
  const int lane = tid & 63;
  const int wv = tid >> 6;
  const int wr = wv >> 2;   // M half (0..1)
  const int wcq = wv & 3;   // N quarter (0..3)

  // fragment LDS offsets (f16 elements), swizzle folded to lane-constant XOR
  const int kpart = ((lane >> 4) * 8) ^ ((lane & 4) << 2);
  const int abase = (lane & 15) * 64 + kpart;
  const int bbase = ((wcq & 1) * 64 + (lane & 15)) * 64 + kpart;

  // stage per-lane source offsets (bytes within a [128][LD] half tile)
  int rowl[2], colb[2];
#pragma unroll
  for (int ld = 0; ld < 2; ++ld) {
    const int doff = (ld * 512 + tid) * 16;
    const int off2 = doff ^ (((doff >> 9) & 1) << 5);
    rowl[ld] = off2 >> 7;
    colb[ld] = off2 & 127;
  }

  const char* Agb = (const char*)Ag;
  const char* Bgb = (const char*)Bg;

  auto stage = [&](int t, int mat, int h) {
    if (t >= NT) return;
    const char* gb = mat ? Bgb : Agb;
    const int ldm2 = (mat ? LDB : LDA) * 2;
    f16* lsl = (mat ? Bls : Als) + ((t & 1) * 2 + h) * 8192 + wv * 512;
#pragma unroll
    for (int ld = 0; ld < 2; ++ld) {
      const char* src =
          gb + (size_t)(h * 128 + rowl[ld]) * ldm2 + (size_t)t * 128 + colb[ld];
      GLL16(src, lsl + ld * 4096);
    }
  };

  // prologue: tile0 {A0,A1,B0,B1}, tile1 {A0,A1,B0} -> 14 loads in flight
  stage(0, 0, 0); stage(0, 0, 1); stage(0, 1, 0); stage(0, 1, 1);
  stage(1, 0, 0); stage(1, 0, 1); stage(1, 1, 0);
  asm volatile("s_waitcnt vmcnt(6)" ::: "memory");  // tile0 resident
  SBAR();
  SFENCE();

  for (int T = 0; T < NT; ++T) {
    const f16* Ab = Als + ((T & 1) * 2 + wr) * 8192;
    const f16* Bb = Bls + ((T & 1) * 2 + (wcq >> 1)) * 8192;
    // ---------------- phase 1 ----------------
    stage(T + 1, 1, 1);
    f16x8 af[8][2], bf[4][2];
#pragma unroll
    for (int m = 0; m < 8; ++m)
#pragma unroll
      for (int s = 0; s < 2; ++s)
        af[m][s] = *(const f16x8*)(Ab + abase + m * 1024 + s * 32);
#pragma unroll
    for (int n = 0; n < 4; ++n)
#pragma unroll
      for (int s = 0; s < 2; ++s)
        bf[n][s] = *(const f16x8*)(Bb + bbase + n * 1024 + s * 32);
    asm volatile("" ::: "memory");
    SBAR();
    asm volatile("s_waitcnt lgkmcnt(0)" ::: "memory");
    SFENCE();
    __builtin_amdgcn_s_setprio(1);
#pragma unroll
    for (int m = 0; m < 4; ++m)
#pragma unroll
      for (int n = 0; n < 4; ++n)
        acc[m][n] = __builtin_amdgcn_mfma_f32_16x16x32_f16(af[m][0], bf[n][0],
                                                           acc[m][n], 0, 0, 0);
    __builtin_amdgcn_s_setprio(0);
    SBAR();
    SFENCE();
    // ---------------- phase 2 ----------------
    stage(T + 2, 0, 0);
    SBAR();
    __builtin_amdgcn_s_setprio(1);
#pragma unroll
    for (int m = 4; m < 8; ++m)
#pragma unroll
      for (int n = 0; n < 4; ++n)
        acc[m][n] = __builtin_amdgcn_mfma_f32_16x16x32_f16(af[m][0], bf[n][0],
                                                           acc[m][n], 0, 0, 0);
    __builtin_amdgcn_s_setprio(0);
    SBAR();
    SFENCE();
    // ---------------- phase 3 ----------------
    stage(T + 2, 0, 1);
    SBAR();
    __builtin_amdgcn_s_setprio(1);
#pragma unroll
    for (int m = 0; m < 4; ++m)
#pragma unroll
      for (int n = 0; n < 4; ++n)
        acc[m][n] = __builtin_amdgcn_mfma_f32_16x16x32_f16(af[m][1], bf[n][1],
                                                           acc[m][n], 0, 0, 0);
    __builtin_amdgcn_s_setprio(0);
    SBAR();
    SFENCE();
    // ---------------- phase 4 ----------------
    stage(T + 2, 1, 0);
    if (T + 2 < NT) {
      asm volatile("s_waitcnt vmcnt(6)" ::: "memory");
    } else {
      asm volatile("s_waitcnt vmcnt(0)" ::: "memory");
    }
    SBAR();
    __builtin_amdgcn_s_setprio(1);
#pragma unroll
    for (int m = 4; m < 8; ++m)
#pragma unroll
      for (int n = 0; n < 4; ++n)
        acc[m][n] = __builtin_amdgcn_mfma_f32_16x16x32_f16(af[m][1], bf[n][1],
                                                           acc[m][n], 0, 0, 0);
    __builtin_amdgcn_s_setprio(0);
    SBAR();
    SFENCE();
  }
}

#define ZERO_ACC8(acc)                                                         \
  f32x4 acc[8][4];                                                             \
  _Pragma("unroll") for (int zi = 0; zi < 8; ++zi)                             \
      _Pragma("unroll") for (int zj = 0; zj < 4; ++zj) {                       \
    f32x4 z = {0.f, 0.f, 0.f, 0.f};                                            \
    acc[zi][zj] = z;                                                           \
  }

// ------------------- old 128x128 2-phase mainloop (for gemm_m) -------------
__device__ __forceinline__ void run_mainloop(const f16* __restrict__ Atile,
                                             const f16* __restrict__ Btile,
                                             int lda, int ldb, int nk,
                                             f16* As, f16* Bs,
                                             f32x4 (&acc)[4][4]) {
  const int tid = threadIdx.x;
  const int lane = tid & 63;
  const int wave = tid >> 6;
  const int wr = wave >> 1, wc = wave & 1;

  auto stage = [&](int buf, int kt) {
#pragma unroll
    for (int j = 0; j < 2; ++j) {
      const int idx = j * 256 + wave * 64 + lane;
      const int row = idx >> 2;
      const int kc = idx & 3;
      GLL16(Atile + (size_t)row * lda + kt * 32 + kc * 8,
            As + buf * TILE_E + (j * 256 + wave * 64) * 8);
      GLL16(Btile + (size_t)row * ldb + kt * 32 + kc * 8,
            Bs + buf * TILE_E + (j * 256 + wave * 64) * 8);
    }
  };

  stage(0, 0);
  __syncthreads();
  for (int kt = 0; kt < nk; ++kt) {
    const int buf = kt & 1;
    if (kt + 1 < nk) stage(buf ^ 1, kt + 1);
    const f16* aB = As + buf * TILE_E;
    const f16* bB = Bs + buf * TILE_E;
    f16x8 af[4], bf[4];
#pragma unroll
    for (int i = 0; i < 4; ++i)
      af[i] = *(const f16x8*)(aB + (wr * 64 + i * 16 + (lane & 15)) * 32 +
                              ((lane >> 4) * 8));
#pragma unroll
    for (int j = 0; j < 4; ++j)
      bf[j] = *(const f16x8*)(bB + (wc * 64 + j * 16 + (lane & 15)) * 32 +
                              ((lane >> 4) * 8));
#pragma unroll
    for (int i = 0; i < 4; ++i)
#pragma unroll
      for (int j = 0; j < 4; ++j)
        acc[i][j] =
            __builtin_amdgcn_mfma_f32_16x16x32_f16(af[i], bf[j], acc[i][j],
                                                   0, 0, 0);
    __syncthreads();
  }
}

#define ZERO_ACC(acc)                                                          \
  f32x4 acc[4][4];                                                             \
  _Pragma("unroll") for (int zi = 0; zi < 4; ++zi)                             \
      _Pragma("unroll") for (int zj = 0; zj < 4; ++zj) {                       \
    f32x4 z = {0.f, 0.f, 0.f, 0.f};                                            \
    acc[zi][zj] = z;                                                           \
  }

// --------------------------- prep kernels ----------------------------------
__global__ void __launch_bounds__(256) k_cvt_x(const float* __restrict__ in,
                                               f16* __restrict__ out) {
  const int i = blockIdx.x * 256 + threadIdx.x;
  float4 v = ((const float4*)in)[i];
  f16x4 h = {(f16)v.x, (f16)v.y, (f16)v.z, (f16)v.w};
  ((f16x4*)out)[i] = h;
}

__global__ void __launch_bounds__(256) k_transpose_w(const float* __restrict__ w,
                                                     f16* __restrict__ wt,
                                                     int cols) {
  const int idx = blockIdx.x * 256 + threadIdx.x;
  const int n = idx >> 9;
  const int c = idx & 511;
  wt[idx] = (f16)w[(size_t)c * cols + n];
}

// --------------------------- GEMM kernels ----------------------------------
// qkv = relu(x @ Wqkv + b); writes q^T,k^T [C][N] f16, v [N][C] f16
// grid: 768 blocks = 6 (col tiles) x 16 (row tiles) x 8 (batch)
__global__ void __launch_bounds__(512, 2)
    k_gemm_qkv(const f16* __restrict__ x16, const f16* __restrict__ wqkvt,
               const float* __restrict__ bqkv, f16* __restrict__ q_t,
               f16* __restrict__ k_t, f16* __restrict__ v16) {
  __shared__ alignas(16) f16 Als[4 * 8192];
  __shared__ alignas(16) f16 Bls[4 * 8192];
  const int l = xcd_remap(blockIdx.x, 768);
  const int bx = l % 6;
  const int rest = l / 6;
  const int by = rest & 15;
  const int b = rest >> 4;
  const f16* Ag = x16 + ((size_t)b * N_ + by * 256) * C_;
  const f16* Bg = wqkvt + (size_t)bx * 256 * C_;
  ZERO_ACC8(acc);
  mainloop8<C_, C_, C_ / 64>(Ag, Bg, Als, Bls, acc);

  const int lane = threadIdx.x & 63, wv = threadIdx.x >> 6;
  const int wr = wv >> 2, wcq = wv & 3;
  const int sec = bx >> 1;  // 0=q 1=k 2=v, uniform per block
  const int colloc = (bx & 1) * 256 + wcq * 64;
  const int rowbase = by * 256 + wr * 128;
#pragma unroll
  for (int n = 0; n < 4; ++n) {
    const int cch = colloc + n * 16 + (lane & 15);
    const float bias = bqkv[sec * 512 + cch];
#pragma unroll
    for (int m = 0; m < 8; ++m) {
      const int n0 = rowbase + m * 16 + ((lane >> 4) << 2);
      f32x4 a = acc[m][n];
      f16x4 h = {(f16)fmaxf(a[0] + bias, 0.f), (f16)fmaxf(a[1] + bias, 0.f),
                 (f16)fmaxf(a[2] + bias, 0.f), (f16)fmaxf(a[3] + bias, 0.f)};
      if (sec == 0) {
        *(f16x4*)(q_t + ((size_t)b * C_ + cch) * N_ + n0) = h;
      } else if (sec == 1) {
        *(f16x4*)(k_t + ((size_t)b * C_ + cch) * N_ + n0) = h;
      } else {
        f16* dst = v16 + ((size_t)b * N_ + n0) * C_ + cch;
        dst[0] = h[0];
        dst[C_] = h[1];
        dst[2 * C_] = h[2];
        dst[3 * C_] = h[3];
      }
    }
  }
}

// scores partial: spart[sp][b][c][d] = sum_{n in split sp} q[n,c]k[n,d]
// grid: 128 blocks = 2 x 2 x (8 batch * 4 splits)
__global__ void __launch_bounds__(512, 2)
    k_gemm_scores(const f16* __restrict__ q_t, const f16* __restrict__ k_t,
                  float* __restrict__ spart) {
  __shared__ alignas(16) f16 Als[4 * 8192];
  __shared__ alignas(16) f16 Bls[4 * 8192];
  const int l = xcd_remap(blockIdx.x, 128);
  const int bx = l & 1;
  const int by = (l >> 1) & 1;
  const int z = l >> 2;
  const int b = z >> 2, sp = z & 3;
  const f16* Ag = q_t + (size_t)b * C_ * N_ + (size_t)(by * 256) * N_ + sp * 1024;
  const f16* Bg = k_t + (size_t)b * C_ * N_ + (size_t)(bx * 256) * N_ + sp * 1024;
  ZERO_ACC8(acc);
  mainloop8<N_, N_, 1024 / 64>(Ag, Bg, Als, Bls, acc);

  const int lane = threadIdx.x & 63, wv = threadIdx.x >> 6;
  const int wr = wv >> 2, wcq = wv & 3;
  float* base = spart + (size_t)(sp * B_ + b) * C_ * C_;
#pragma unroll
  for (int n = 0; n < 4; ++n) {
    const int d = bx * 256 + wcq * 64 + n * 16 + (lane & 15);
#pragma unroll
    for (int m = 0; m < 8; ++m) {
      const int c0 = by * 256 + wr * 128 + m * 16 + ((lane >> 4) << 2);
#pragma unroll
      for (int r = 0; r < 4; ++r)
        base[(size_t)(c0 + r) * C_ + d] = acc[m][n][r];
    }
  }
}

// attn = softmax(sum(spart)*scale, axis=-1) * adj  -> f16
__global__ void __launch_bounds__(256)
    k_softmax_gate(const float* __restrict__ spart,
                   const float* __restrict__ adj, f16* __restrict__ attn) {
  const int b = blockIdx.x >> 9, c = blockIdx.x & 511;
  const int tid = threadIdx.x;
  const size_t ro = ((size_t)b * C_ + c) * C_;
  float s0 = 0.f, s1 = 0.f;
#pragma unroll
  for (int sp = 0; sp < 4; ++sp) {
    const float* p = spart + (size_t)sp * B_ * C_ * C_ + ro;
    s0 += p[tid];
    s1 += p[tid + 256];
  }
  const float scale = 0.044194173824159216f;  // 1/sqrt(512)
  const float v0 = s0 * scale, v1 = s1 * scale;

  __shared__ float red[256];
  red[tid] = fmaxf(v0, v1);
  __syncthreads();
  for (int s = 128; s > 0; s >>= 1) {
    if (tid < s) red[tid] = fmaxf(red[tid], red[tid + s]);
    __syncthreads();
  }
  const float mx = red[0];
  __syncthreads();
  const float e0 = __expf(v0 - mx), e1 = __expf(v1 - mx);
  red[tid] = e0 + e1;
  __syncthreads();
  for (int s = 128; s > 0; s >>= 1) {
    if (tid < s) red[tid] += red[tid + s];
    __syncthreads();
  }
  const float inv = 1.0f / red[0];
  attn[ro + tid] = (f16)(e0 * inv * adj[ro + tid]);
  attn[ro + tid + 256] = (f16)(e1 * inv * adj[ro + tid + 256]);
}

// M^T[e][c] = sum_d attn[c][d] * Wo[d][e]   (small: keep 128^2 2-phase)
__global__ void __launch_bounds__(256)
    k_gemm_m(const f16* __restrict__ attn, const f16* __restrict__ wot,
             f16* __restrict__ mt) {
  __shared__ alignas(16) f16 As[2 * TILE_E];
  __shared__ alignas(16) f16 Bs[2 * TILE_E];
  const int b = blockIdx.z;
  const f16* Atile = attn + (size_t)b * C_ * C_ + (size_t)blockIdx.y * 128 * C_;
  const f16* Btile = wot + (size_t)blockIdx.x * 128 * C_;
  ZERO_ACC(acc);
  run_mainloop(Atile, Btile, C_, C_, C_ / 32, As, Bs, acc);

  const int tid = threadIdx.x, lane = tid & 63, wave = tid >> 6;
  const int wr = wave >> 1, wc = wave & 1;
  f16* base = mt + (size_t)b * C_ * C_;
  const int colbase = blockIdx.x * 128 + wc * 64;
  const int rowbase = blockIdx.y * 128 + wr * 64;
#pragma unroll
  for (int j = 0; j < 4; ++j) {
    const int e = colbase + j * 16 + (lane & 15);
#pragma unroll
    for (int i = 0; i < 4; ++i) {
      const int c0 = rowbase + i * 16 + ((lane >> 4) << 2);
      f32x4 a = acc[i][j];
      f16x4 h = {(f16)a[0], (f16)a[1], (f16)a[2], (f16)a[3]};
      *(f16x4*)(base + (size_t)e * C_ + c0) = h;  // transposed store
    }
  }
}

// out[n][e] = sum_c v[n][c] * M[c][e] + bo[e]   (fp32 out)
// grid: 256 blocks = 2 x 16 x 8
__global__ void __launch_bounds__(512, 2)
    k_gemm_out(const f16* __restrict__ v16, const f16* __restrict__ mt,
               const float* __restrict__ bo, float* __restrict__ out) {
  __shared__ alignas(16) f16 Als[4 * 8192];
  __shared__ alignas(16) f16 Bls[4 * 8192];
  const int l = xcd_remap(blockIdx.x, 256);
  const int bx = l & 1;
  const int by = (l >> 1) & 15;
  const int b = l >> 5;
  const f16* Ag = v16 + ((size_t)b * N_ + by * 256) * C_;
  const f16* Bg = mt + (size_t)b * C_ * C_ + (size_t)(bx * 256) * C_;
  ZERO_ACC8(acc);
  mainloop8<C_, C_, C_ / 64>(Ag, Bg, Als, Bls, acc);

  const int lane = threadIdx.x & 63, wv = threadIdx.x >> 6;
  const int wr = wv >> 2, wcq = wv & 3;
  float* base = out + (size_t)b * N_ * C_;
#pragma unroll
  for (int n = 0; n < 4; ++n) {
    const int e = bx * 256 + wcq * 64 + n * 16 + (lane & 15);
    const float bias = bo[e];
#pragma unroll
    for (int m = 0; m < 8; ++m) {
      const int n0 = by * 256 + wr * 128 + m * 16 + ((lane >> 4) << 2);
#pragma unroll
      for (int r = 0; r < 4; ++r)
        base[(size_t)(n0 + r) * C_ + e] = acc[m][n][r] + bias;
    }
  }
}

// ---------------------------------------------------------------------------
extern "C" void kernel_launch(void* const* d_in, const int* in_sizes, int n_in,
                              void* d_out, int out_size, void* d_ws,
                              size_t ws_size, hipStream_t stream) {
  const float* x = (const float*)d_in[0];
  const float* adj = (const float*)d_in[1];
  const float* Wqkv = (const float*)d_in[2];
  const float* bqkv = (const float*)d_in[3];
  const float* Wo = (const float*)d_in[4];
  const float* bo = (const float*)d_in[5];
  float* out = (float*)d_out;

  char* ws = (char*)d_ws;
  size_t off = 0;
  auto carve = [&](size_t bytes) -> char* {
    char* p = ws + off;
    off += (bytes + 255) & ~(size_t)255;
    return p;
  };
  f16* x16 = (f16*)carve((size_t)B_ * N_ * C_ * 2);       // 33.6 MB
  f16* wqkvt = (f16*)carve((size_t)3 * C_ * C_ * 2);      // 1.6 MB
  f16* wot = (f16*)carve((size_t)C_ * C_ * 2);            // 0.5 MB
  f16* q_t = (f16*)carve((size_t)B_ * C_ * N_ * 2);       // 33.6 MB
  f16* k_t = (f16*)carve((size_t)B_ * C_ * N_ * 2);       // 33.6 MB
  f16* v16 = (f16*)carve((size_t)B_ * N_ * C_ * 2);       // 33.6 MB
  // aliases over dead buffers (stream order guarantees liveness separation)
  float* spart = (float*)x16;   // 33.6 MB, x16 dead after qkv
  f16* attn16 = k_t;            // 4.2 MB, k_t dead after scores
  f16* mt16 = q_t;              // 4.2 MB, q_t dead after scores

  k_cvt_x<<<(B_ * N_ * C_ / 4) / 256, 256, 0, stream>>>(x, x16);
  k_transpose_w<<<(C_ * 3 * C_) / 256, 256, 0, stream>>>(Wqkv, wqkvt, 3 * C_);
  k_transpose_w<<<(C_ * C_) / 256, 256, 0, stream>>>(Wo, wot, C_);
  k_gemm_qkv<<<768, 512, 0, stream>>>(x16, wqkvt, bqkv, q_t, k_t, v16);
  k_gemm_scores<<<128, 512, 0, stream>>>(q_t, k_t, spart);
  k_softmax_gate<<<B_ * C_, 256, 0, stream>>>(spart, adj, attn16);
  k_gemm_m<<<dim3(4, 4, B_), 256, 0, stream>>>(attn16, wot, mt16);
  k_gemm_out<<<256, 512, 0, stream>>>(v16, mt16, bo, out);
}